// Round 2
// baseline (3290.808 us; speedup 1.0000x reference)
//
#include <hip/hip_runtime.h>
#include <hip/hip_bf16.h>
#include <stdint.h>

// Problem constants
#define B   32
#define TX  128
#define TY  64
#define VCB 50000
#define D   128
#define H   256
#define G4  1024   // 4*H
#define TT  192    // TX+TY

typedef unsigned short ushort_t;

__device__ __forceinline__ float b2f(ushort_t u) {
    union { unsigned int i; float f; } v;
    v.i = ((unsigned int)u) << 16;
    return v.f;
}

__device__ __forceinline__ ushort_t f2b(float f) {
    union { float f; unsigned int i; } v;
    v.f = f;
    unsigned int i = v.i;
    unsigned int r = (i + 0x7fffu + ((i >> 16) & 1u)) >> 16;  // RNE
    return (ushort_t)r;
}

// Flag-aware load: isf32 ? fp32 array : bf16 array. Branch is wave-uniform.
__device__ __forceinline__ float ldf(const void* p, size_t i, int isf32) {
    if (isf32) return ((const float*)p)[i];
    return b2f(((const ushort_t*)p)[i]);
}

// ---------------------------------------------------------------------------
// Kernel 0: dtype detection. Interpret E's first 4096 u16 as bf16; genuine
// bf16 data (normal*0.05) has max|v| ~0.25. fp32 data's low-half u16s have
// random exponent bits -> max|v| is astronomically large. flag=1 => fp32.
// ---------------------------------------------------------------------------
__global__ __launch_bounds__(256) void detect_dtype(const ushort_t* __restrict__ E16,
                                                    int* __restrict__ flag) {
    __shared__ float red[256];
    int tid = threadIdx.x;
    float m = 0.f;
#pragma unroll
    for (int j = 0; j < 16; ++j) {
        float v = fabsf(b2f(E16[tid * 16 + j]));
        if (v > m) m = v;   // NaN-decodes ignored; plenty of huge finite ones
    }
    red[tid] = m;
    __syncthreads();
    for (int s = 128; s > 0; s >>= 1) {
        if (tid < s && red[tid + s] > red[tid]) red[tid] = red[tid + s];
        __syncthreads();
    }
    if (tid == 0) flag[0] = (red[0] > 1.0f) ? 1 : 0;
}

// ---------------------------------------------------------------------------
// Kernel 0b: canonicalize LSTM weights/biases to fp32 (exact either way).
// ---------------------------------------------------------------------------
__global__ __launch_bounds__(256) void canon_w(const void* __restrict__ We,
                                               const void* __restrict__ be,
                                               const void* __restrict__ Wd,
                                               const void* __restrict__ bd,
                                               float* __restrict__ Wce,
                                               float* __restrict__ bce,
                                               float* __restrict__ Wcd,
                                               float* __restrict__ bcd,
                                               const int* __restrict__ flag) {
    int isf32 = *flag;
    int i = blockIdx.x * 256 + threadIdx.x;
    const int NW = (D + H) * G4;   // 393216
    if (i < NW) {
        Wce[i] = ldf(We, i, isf32);
        Wcd[i] = ldf(Wd, i, isf32);
    }
    if (i < G4) {
        bce[i] = ldf(be, i, isf32);
        bcd[i] = ldf(bd, i, isf32);
    }
}

// ---------------------------------------------------------------------------
// Kernel 1: transpose W_proj (H x V) -> WpT (V x H) bf16, k-contiguous rows.
// ---------------------------------------------------------------------------
__global__ __launch_bounds__(256) void transpose_wp(const void* __restrict__ Wp,
                                                    ushort_t* __restrict__ WpT,
                                                    const int* __restrict__ flag) {
    int isf32 = *flag;
    int v0 = blockIdx.x * 64;
    int k0 = blockIdx.y * 64;
    __shared__ ushort_t tile[64][65];
    int tid = threadIdx.x;
    int vl = tid & 63, p0 = tid >> 6;     // p0 in [0,4)
    for (int p = 0; p < 16; ++p) {
        int k = k0 + p0 + p * 4;          // k < 256 always
        int v = v0 + vl;
        float x = (v < VCB) ? ldf(Wp, (size_t)k * VCB + v, isf32) : 0.f;
        tile[p0 + p * 4][vl] = f2b(x);
    }
    __syncthreads();
    int kl = tid & 63, q0 = tid >> 6;
    for (int p = 0; p < 16; ++p) {
        int v = v0 + q0 + p * 4;
        if (v < VCB) WpT[(size_t)v * H + (k0 + kl)] = tile[kl][q0 + p * 4];
    }
}

// ---------------------------------------------------------------------------
// Kernel 2: embedding gather + x-part of gate GEMM for all 192 steps (fp32).
// xz[t][b][g] = sum_k emb(t,b,k) * Wx[k][g] + bias[g]
// ---------------------------------------------------------------------------
__global__ __launch_bounds__(128) void embed_xw(const int* __restrict__ enc_in,
                                                const int* __restrict__ dec_in,
                                                const void* __restrict__ E,
                                                const float* __restrict__ Wce,
                                                const float* __restrict__ bce,
                                                const float* __restrict__ Wcd,
                                                const float* __restrict__ bcd,
                                                float* __restrict__ xz,
                                                const int* __restrict__ flag) {
    int isf32 = *flag;
    int t  = blockIdx.y;          // 0..191
    int n0 = blockIdx.x * 64;     // 16 n-slices
    int tid = threadIdx.x;        // 0..127 (= k index)
    __shared__ float embT[D][33]; // [k][b], padded
    __shared__ int tok[B];

    const float* Wc   = (t < TX) ? Wce : Wcd;
    const float* bias = (t < TX) ? bce : bcd;

    if (tid < B)
        tok[tid] = (t < TX) ? enc_in[tid * TX + t] : dec_in[tid * TY + (t - TX)];
    __syncthreads();

    for (int p = 0; p < B; ++p)
        embT[tid][p] = ldf(E, (size_t)tok[p] * D + tid, isf32);
    __syncthreads();

    int nl = tid & 31;            // n-pair index
    int bg = tid >> 5;            // 0..3
    int n  = n0 + nl * 2;
    int b0 = bg * 8;
    float acc[8][2];
    float bi0 = bias[n], bi1 = bias[n + 1];
#pragma unroll
    for (int r = 0; r < 8; ++r) { acc[r][0] = bi0; acc[r][1] = bi1; }

    for (int k = 0; k < D; ++k) {
        const float* wr = Wc + (size_t)k * G4 + n;
        float w0 = wr[0], w1 = wr[1];
#pragma unroll
        for (int r = 0; r < 8; ++r) {
            float e = embT[k][b0 + r];
            acc[r][0] += e * w0;
            acc[r][1] += e * w1;
        }
    }
#pragma unroll
    for (int r = 0; r < 8; ++r) {
        float* o = xz + ((size_t)t * B + (b0 + r)) * G4 + n;
        o[0] = acc[r][0];
        o[1] = acc[r][1];
    }
}

// ---------------------------------------------------------------------------
// Kernel 3: one LSTM step (launched 192x). Block g owns h-columns {2g,2g+1}.
// z = xz[t] + h_in @ Wh (fp32); gate math fp32; h double-buffered.
// ---------------------------------------------------------------------------
__global__ __launch_bounds__(256) void lstm_step(const float* __restrict__ Wc,    // (D+H, 4H) fp32
                                                 const float* __restrict__ xz_t,  // (B, 4H)
                                                 const float* __restrict__ h_in,  // (B, H)
                                                 float* __restrict__ h_out,       // (B, H)
                                                 float* __restrict__ c,           // (B, H)
                                                 const int* __restrict__ len,     // null => decoder
                                                 int t_enc,
                                                 ushort_t* __restrict__ hs,       // null for encoder
                                                 int td) {
    int g  = blockIdx.x;    // 0..127
    int n0 = g * 2;
    int tid = threadIdx.x;
    __shared__ float hT[H][33];     // [k][b], padded
    __shared__ float zbuf[8][32];   // [u][b]

    for (int p = 0; p < B; ++p)
        hT[tid][p] = h_in[p * H + tid];
    __syncthreads();

    int b  = tid & 31;
    int u  = tid >> 5;        // u = nl*4 + q
    int q  = u & 3;
    int nl = u >> 2;
    int col = q * H + n0 + nl;

    float acc = xz_t[(size_t)b * G4 + col];
    const float* Wh = Wc + (size_t)D * G4;   // h-part rows [128, 384)
#pragma unroll 4
    for (int k = 0; k < H; ++k)
        acc += hT[k][b] * Wh[(size_t)k * G4 + col];

    zbuf[u][b] = acc;
    __syncthreads();

    if (tid < 64) {
        int bb = tid & 31;
        int nn = tid >> 5;    // 0..1
        int n = n0 + nn;
        float zi = zbuf[nn * 4 + 0][bb];
        float zj = zbuf[nn * 4 + 1][bb];
        float zf = zbuf[nn * 4 + 2][bb];
        float zo = zbuf[nn * 4 + 3][bb];
        float si = 1.f / (1.f + __expf(-zi));
        float sf = 1.f / (1.f + __expf(-(zf + 1.0f)));   // FORGET_BIAS = 1
        float so = 1.f / (1.f + __expf(-zo));
        float tj = tanhf(zj);
        size_t ci = (size_t)bb * H + n;
        float cold = c[ci];
        float nc = cold * sf + si * tj;
        float nh = tanhf(nc) * so;
        if (len) {  // encoder sequence-length mask: freeze state past length
            if (t_enc >= len[bb]) { nc = cold; nh = h_in[ci]; }
        }
        c[ci] = nc;
        h_out[ci] = nh;
        if (hs) hs[((size_t)bb * TY + td) * H + n] = f2b(nh);
    }
}

// ---------------------------------------------------------------------------
// Kernel 4: projection GEMM  out[m][v] = sum_k hs[m][k] * WpT[v][k]
// M=2048, N=50000, K=256. 128x128 tiles, 4 waves, 16x16x32 bf16 MFMA.
// ---------------------------------------------------------------------------
typedef __attribute__((ext_vector_type(8))) short bf16x8;
typedef __attribute__((ext_vector_type(4))) float f32x4;

__global__ __launch_bounds__(256) void proj_gemm(const ushort_t* __restrict__ hs,
                                                 const ushort_t* __restrict__ WpT,
                                                 void* __restrict__ outv,
                                                 const int* __restrict__ flag) {
    int isf32 = *flag;
    int bx = blockIdx.x;  // 391 n-tiles
    int by = blockIdx.y;  // 16 m-tiles
    int m0 = by * 128, n0 = bx * 128;
    int tid = threadIdx.x;
    int w = tid >> 6, l = tid & 63;
    int qm = (w & 1) * 64, qn = (w >> 1) * 64;

    __shared__ __attribute__((aligned(16))) ushort_t As[128 * 32];
    __shared__ __attribute__((aligned(16))) ushort_t Bs[128 * 32];

    f32x4 acc[4][4] = {};
    int lr = l & 15, lg = l >> 4;

    for (int kk = 0; kk < 8; ++kk) {
        int k0 = kk * 32;
        __syncthreads();
        {
            int row = tid >> 2;
            int off = (tid & 3) * 8;   // ushort offset, 16B granular
            *(uint4*)&As[row * 32 + off] =
                *(const uint4*)&hs[((size_t)(m0 + row)) * H + k0 + off];
            *(uint4*)&As[(row + 64) * 32 + off] =
                *(const uint4*)&hs[((size_t)(m0 + row + 64)) * H + k0 + off];
            int nr0 = n0 + row;       if (nr0 > VCB - 1) nr0 = VCB - 1;
            int nr1 = n0 + row + 64;  if (nr1 > VCB - 1) nr1 = VCB - 1;
            *(uint4*)&Bs[row * 32 + off] =
                *(const uint4*)&WpT[(size_t)nr0 * H + k0 + off];
            *(uint4*)&Bs[(row + 64) * 32 + off] =
                *(const uint4*)&WpT[(size_t)nr1 * H + k0 + off];
        }
        __syncthreads();

        bf16x8 a[4], bf[4];
#pragma unroll
        for (int i = 0; i < 4; ++i)
            a[i] = *(const bf16x8*)&As[(qm + 16 * i + lr) * 32 + lg * 8];
#pragma unroll
        for (int j = 0; j < 4; ++j)
            bf[j] = *(const bf16x8*)&Bs[(qn + 16 * j + lr) * 32 + lg * 8];
#pragma unroll
        for (int i = 0; i < 4; ++i)
#pragma unroll
            for (int j = 0; j < 4; ++j)
                acc[i][j] = __builtin_amdgcn_mfma_f32_16x16x32_bf16(a[i], bf[j], acc[i][j], 0, 0, 0);
    }

    if (isf32) {
        float* out = (float*)outv;
#pragma unroll
        for (int i = 0; i < 4; ++i)
#pragma unroll
            for (int j = 0; j < 4; ++j) {
                int mrow = m0 + qm + 16 * i + lg * 4;
                int ncol = n0 + qn + 16 * j + lr;
                if (ncol < VCB) {
#pragma unroll
                    for (int r = 0; r < 4; ++r)
                        out[(size_t)(mrow + r) * VCB + ncol] = acc[i][j][r];
                }
            }
    } else {
        ushort_t* out = (ushort_t*)outv;
#pragma unroll
        for (int i = 0; i < 4; ++i)
#pragma unroll
            for (int j = 0; j < 4; ++j) {
                int mrow = m0 + qm + 16 * i + lg * 4;
                int ncol = n0 + qn + 16 * j + lr;
                if (ncol < VCB) {
#pragma unroll
                    for (int r = 0; r < 4; ++r)
                        out[(size_t)(mrow + r) * VCB + ncol] = f2b(acc[i][j][r]);
                }
            }
    }
}

// ---------------------------------------------------------------------------
extern "C" void kernel_launch(void* const* d_in, const int* in_sizes, int n_in,
                              void* d_out, int out_size, void* d_ws, size_t ws_size,
                              hipStream_t stream) {
    const int* enc_in = (const int*)d_in[0];
    const int* dec_in = (const int*)d_in[1];
    const int* lens   = (const int*)d_in[2];
    const void* E      = d_in[3];
    const void* W_enc  = d_in[4];
    const void* b_enc  = d_in[5];
    const void* W_dec  = d_in[6];
    const void* b_dec  = d_in[7];
    const void* W_proj = d_in[8];

    char* ws = (char*)d_ws;
    size_t o = 0;
    int*   flag = (int*)(ws + o);        o += 256;
    float* xz   = (float*)(ws + o);      o += (size_t)TT * B * G4 * 4;     // 25.17 MB
    ushort_t* WpT = (ushort_t*)(ws + o); o += (size_t)VCB * H * 2;         // 25.6 MB
    float* Wce  = (float*)(ws + o);      o += (size_t)(D + H) * G4 * 4;    // 1.57 MB
    float* Wcd  = (float*)(ws + o);      o += (size_t)(D + H) * G4 * 4;    // 1.57 MB
    float* bce  = (float*)(ws + o);      o += 4096;
    float* bcd  = (float*)(ws + o);      o += 4096;
    float* c    = (float*)(ws + o);      o += (size_t)B * H * 4;
    float* h0   = (float*)(ws + o);      o += (size_t)B * H * 4;
    float* h1   = (float*)(ws + o);      o += (size_t)B * H * 4;
    ushort_t* hs = (ushort_t*)(ws + o);  o += (size_t)B * TY * H * 2;      // 1 MB

    detect_dtype<<<1, 256, 0, stream>>>((const ushort_t*)E, flag);
    hipMemsetAsync(c, 0, (size_t)B * H * 4 * 2, stream);   // zero c and h0
    canon_w<<<1536, 256, 0, stream>>>(W_enc, b_enc, W_dec, b_dec,
                                      Wce, bce, Wcd, bcd, flag);
    transpose_wp<<<dim3(782, 4), 256, 0, stream>>>(W_proj, WpT, flag);
    embed_xw<<<dim3(16, TT), 128, 0, stream>>>(enc_in, dec_in, E,
                                               Wce, bce, Wcd, bcd, xz, flag);

    for (int t = 0; t < TX; ++t) {
        const float* hi = (t & 1) ? h1 : h0;
        float*       ho = (t & 1) ? h0 : h1;
        lstm_step<<<128, 256, 0, stream>>>(Wce, xz + (size_t)t * B * G4,
                                           hi, ho, c, lens, t, (ushort_t*)nullptr, 0);
    }
    for (int td = 0; td < TY; ++td) {
        int t = TX + td;
        const float* hi = (t & 1) ? h1 : h0;
        float*       ho = (t & 1) ? h0 : h1;
        lstm_step<<<128, 256, 0, stream>>>(Wcd, xz + (size_t)t * B * G4,
                                           hi, ho, c, (const int*)nullptr, 0, hs, td);
    }

    proj_gemm<<<dim3(391, 16), 256, 0, stream>>>(hs, WpT, d_out, flag);
}